// Round 3
// baseline (124.003 us; speedup 1.0000x reference)
//
#include <hip/hip_runtime.h>
#include <hip/hip_fp16.h>

// Fused: embedding gather -> masked mean -> ReLU -> linear(20x50)+bias
//   VOCAB=100000, DIM=50, B=4096, L=512, OUT=20
// R2 post-mortem: f32 gather was L2-miss-bound (130MB FETCH @ ~3TB/s random-line).
// R3: convert table to fp16 in ws (halves miss bytes AND doubles effective L2
// capacity), keep row-major coalesced gathers (2 rows / wave-instruction).

#define LMAX   512
#define DIMV   50
#define OUTV   20
#define VOCABSZ 100000

// ---- Kernel 1: f32 table -> f16 table in workspace (streaming, 8 elem/thr) ----
__global__ __launch_bounds__(256) void cvt_table_f16(
    const float* __restrict__ emb, __half* __restrict__ tab)
{
    const int i = (blockIdx.x * 256 + threadIdx.x) * 8;
    if (i >= VOCABSZ * DIMV) return;            // 5,000,000 % 8 == 0
    const float4 a = *reinterpret_cast<const float4*>(emb + i);
    const float4 b = *reinterpret_cast<const float4*>(emb + i + 4);
    __half2 h[4];
    h[0] = __floats2half2_rn(a.x, a.y);
    h[1] = __floats2half2_rn(a.z, a.w);
    h[2] = __floats2half2_rn(b.x, b.y);
    h[3] = __floats2half2_rn(b.z, b.w);
    *reinterpret_cast<float4*>(tab + i) = *reinterpret_cast<const float4*>(h);
}

// ---- Kernel 2: fused gather/mean/relu/linear ----
// Per block: one sample. 4 waves. Each wave-instruction reads TWO rows:
//   lanes 0..24  (slot 0) read half2 j of token 2p
//   lanes 32..56 (slot 1) read half2 j of token 2p+1
// so each global instr touches 2x100B contiguous = ~4 cache lines (TA-friendly).
__global__ __launch_bounds__(256) void fused_embed_mean_linear_f16(
    const int*   __restrict__ x,
    const int*   __restrict__ lengths,
    const __half* __restrict__ tab,
    const float* __restrict__ W,
    const float* __restrict__ bias,
    float*       __restrict__ out)
{
    const int b    = blockIdx.x;
    const int tid  = threadIdx.x;
    const int wave = tid >> 6;
    const int lane = tid & 63;
    const int slot = lane >> 5;      // 0 = even token, 1 = odd token
    const int j    = lane & 31;      // half2 index within row; active j<25

    __shared__ int    sidx[LMAX];
    __shared__ float2 sacc[4][25];
    __shared__ float  srep[DIMV];

    const int len = lengths[b];

    // Stage token indices (coalesced).
    const int xbase = b * LMAX;
    for (int i = tid; i < len; i += 256) sidx[i] = x[xbase + i];
    __syncthreads();

    float2 acc0 = {0.f, 0.f}, acc1 = {0.f, 0.f};
    if (j < 25) {
        const int np = (len + 1) >> 1;          // token pairs
        int p = wave;                           // waves interleave pairs by 4
        // Main loop: 8 gathers in flight per wave (16 tokens / wave / iter).
        for (; p + 28 < np; p += 32) {
            #pragma unroll
            for (int u = 0; u < 8; u += 2) {
                const int ta = 2 * (p + 4 * u)       + slot;
                const int tb = 2 * (p + 4 * (u + 1)) + slot;
                float2 fa = {0.f, 0.f}, fb = {0.f, 0.f};
                if (ta < len) {
                    const __half2 h = *reinterpret_cast<const __half2*>(
                        tab + sidx[ta] * DIMV + 2 * j);
                    fa.x = __low2float(h); fa.y = __high2float(h);
                }
                if (tb < len) {
                    const __half2 h = *reinterpret_cast<const __half2*>(
                        tab + sidx[tb] * DIMV + 2 * j);
                    fb.x = __low2float(h); fb.y = __high2float(h);
                }
                acc0.x += fa.x; acc0.y += fa.y;
                acc1.x += fb.x; acc1.y += fb.y;
            }
        }
        // Tail
        for (; p < np; p += 4) {
            const int t = 2 * p + slot;
            if (t < len) {
                const __half2 h = *reinterpret_cast<const __half2*>(
                    tab + sidx[t] * DIMV + 2 * j);
                acc0.x += __low2float(h); acc0.y += __high2float(h);
            }
        }
    }
    acc0.x += acc1.x; acc0.y += acc1.y;
    // Combine slot 1 into slot 0 (lane l gets lane l+32).
    acc0.x += __shfl_down(acc0.x, 32);
    acc0.y += __shfl_down(acc0.y, 32);
    if (slot == 0 && j < 25) sacc[wave][j] = acc0;
    __syncthreads();

    // Cross-wave reduce + mean + ReLU (dims 2t, 2t+1 per thread t<25).
    if (tid < 25) {
        float2 s = sacc[0][tid];
        #pragma unroll
        for (int w = 1; w < 4; ++w) { s.x += sacc[w][tid].x; s.y += sacc[w][tid].y; }
        const float inv = 1.0f / (float)len;
        srep[2 * tid]     = fmaxf(s.x * inv, 0.f);
        srep[2 * tid + 1] = fmaxf(s.y * inv, 0.f);
    }
    __syncthreads();

    // Tiny matvec: 20 outputs x 50-dot (W is 4KB, L1-resident).
    if (tid < OUTV) {
        float s = bias[tid];
        const float* wr = W + tid * DIMV;
        #pragma unroll
        for (int d = 0; d < DIMV; ++d) s += srep[d] * wr[d];
        out[b * OUTV + tid] = s;
    }
}

extern "C" void kernel_launch(void* const* d_in, const int* in_sizes, int n_in,
                              void* d_out, int out_size, void* d_ws, size_t ws_size,
                              hipStream_t stream) {
    const int*   x       = (const int*)  d_in[0];
    const int*   lengths = (const int*)  d_in[1];
    const float* emb     = (const float*)d_in[2];
    const float* W       = (const float*)d_in[3];
    const float* bias    = (const float*)d_in[4];
    float*  out = (float*)d_out;
    __half* tab = (__half*)d_ws;                 // 10 MB fp16 table

    const int B = in_sizes[1];                   // 4096

    const int nconv = (VOCABSZ * DIMV) / 8;      // 625,000 threads
    cvt_table_f16<<<(nconv + 255) / 256, 256, 0, stream>>>(emb, tab);
    fused_embed_mean_linear_f16<<<B, 256, 0, stream>>>(x, lengths, tab, W, bias, out);
}

// Round 4
// 98.823 us; speedup vs baseline: 1.2548x; 1.2548x over previous
//
#include <hip/hip_runtime.h>
#include <hip/hip_fp16.h>

// Fused: embedding gather -> masked mean -> ReLU -> linear(20x50)+bias
//   VOCAB=100000, DIM=50, B=4096, L=512, OUT=20
// R3 post-mortem: NOT miss-byte bound (FETCH halved, time rose). Floor is
// per-token instruction work + predication. R4: padded 128B f16 rows in ws,
// 4 tokens per wave-instruction (16 lanes x dwordx2 each), zero-row padding
// kills all branches, shift-only addressing, 8 chunks in flight.

#define LMAX    512
#define DIMV    50
#define OUTV    20
#define VOCABSZ 100000
#define RSTRIDE 64     // padded row stride in halves (128 B)

struct __align__(8) H4 { __half2 a, b; };   // 4 halves = 8 B

// ---- Kernel 1: build padded f16 table in ws (+1 zero row at index VOCABSZ) ----
// thread t: row r = t>>4, chunk q = t&15 -> halves 4q..4q+3 (dims >=50 zero).
__global__ __launch_bounds__(256) void build_tab(
    const float* __restrict__ emb, __half* __restrict__ tab)
{
    const int t = blockIdx.x * 256 + threadIdx.x;
    const int r = t >> 4;
    const int q = t & 15;
    if (r > VOCABSZ) return;
    float4 v = {0.f, 0.f, 0.f, 0.f};
    if (r < VOCABSZ) {
        const float* src = emb + r * DIMV + q * 4;   // 8B-aligned (r*200 % 8 == 0)
        if (q < 12) {
            float2 a = *reinterpret_cast<const float2*>(src);
            float2 c = *reinterpret_cast<const float2*>(src + 2);
            v.x = a.x; v.y = a.y; v.z = c.x; v.w = c.y;
        } else if (q == 12) {                        // dims 48,49
            float2 a = *reinterpret_cast<const float2*>(src);
            v.x = a.x; v.y = a.y;
        }
    }
    H4 h;
    h.a = __floats2half2_rn(v.x, v.y);
    h.b = __floats2half2_rn(v.z, v.w);
    *reinterpret_cast<H4*>(tab + r * RSTRIDE + q * 4) = h;
}

__device__ inline void accum(float4& a, const H4& h) {
    float2 f0 = __half22float2(h.a);
    float2 f1 = __half22float2(h.b);
    a.x += f0.x; a.y += f0.y; a.z += f1.x; a.w += f1.y;
}

// ---- Kernel 2: fused gather/mean/relu/linear. One block per sample. ----
// lane = 16*rg + cl: row-group rg (token-in-chunk), column cl (4 halves).
// One load instruction = 4 tokens x 128 B, fully coalesced, branch-free.
__global__ __launch_bounds__(256) void fused_gather(
    const int*    __restrict__ x,
    const int*    __restrict__ lengths,
    const __half* __restrict__ tab,
    const float*  __restrict__ W,
    const float*  __restrict__ bias,
    float*        __restrict__ out)
{
    const int b    = blockIdx.x;
    const int tid  = threadIdx.x;
    const int wave = tid >> 6;
    const int lane = tid & 63;
    const int rg   = lane >> 4;     // which row of the 4-token chunk
    const int cl   = lane & 15;     // 4-half column within row

    __shared__ int   sidx[LMAX];
    __shared__ float sacc[4][64];
    __shared__ float srep[DIMV];

    const int len = lengths[b];

    // Stage all 512 indices; tokens >= len point at the zero row (branch-free hot loop).
    const int xbase = b * LMAX;
    #pragma unroll
    for (int i = 0; i < LMAX; i += 256) {
        const int ii = i + tid;
        const int v  = x[xbase + ii];
        sidx[ii] = (ii < len) ? v : VOCABSZ;
    }
    __syncthreads();

    const __half* tabc = tab + cl * 4;       // lane-constant column base
    const int nchunk = (len + 3) >> 2;       // 4-token chunks
    float4 acc = {0.f, 0.f, 0.f, 0.f};

    int c = wave;
    // 8 chunks (32 tokens, 8x512B loads) in flight per wave.
    for (; c + 28 < nchunk; c += 32) {
        int i0 = sidx[(c     ) * 4 + rg];
        int i1 = sidx[(c +  4) * 4 + rg];
        int i2 = sidx[(c +  8) * 4 + rg];
        int i3 = sidx[(c + 12) * 4 + rg];
        int i4 = sidx[(c + 16) * 4 + rg];
        int i5 = sidx[(c + 20) * 4 + rg];
        int i6 = sidx[(c + 24) * 4 + rg];
        int i7 = sidx[(c + 28) * 4 + rg];
        H4 h0 = *reinterpret_cast<const H4*>(tabc + (i0 << 6));
        H4 h1 = *reinterpret_cast<const H4*>(tabc + (i1 << 6));
        H4 h2 = *reinterpret_cast<const H4*>(tabc + (i2 << 6));
        H4 h3 = *reinterpret_cast<const H4*>(tabc + (i3 << 6));
        H4 h4 = *reinterpret_cast<const H4*>(tabc + (i4 << 6));
        H4 h5 = *reinterpret_cast<const H4*>(tabc + (i5 << 6));
        H4 h6 = *reinterpret_cast<const H4*>(tabc + (i6 << 6));
        H4 h7 = *reinterpret_cast<const H4*>(tabc + (i7 << 6));
        accum(acc, h0); accum(acc, h1); accum(acc, h2); accum(acc, h3);
        accum(acc, h4); accum(acc, h5); accum(acc, h6); accum(acc, h7);
    }
    for (; c < nchunk; c += 4) {
        int i0 = sidx[c * 4 + rg];
        H4 h0 = *reinterpret_cast<const H4*>(tabc + (i0 << 6));
        accum(acc, h0);
    }

    // Sum the 4 row-groups (butterfly over lane bits 4,5). Lanes 0-15 hold result.
    acc.x += __shfl_xor(acc.x, 16); acc.y += __shfl_xor(acc.y, 16);
    acc.z += __shfl_xor(acc.z, 16); acc.w += __shfl_xor(acc.w, 16);
    acc.x += __shfl_xor(acc.x, 32); acc.y += __shfl_xor(acc.y, 32);
    acc.z += __shfl_xor(acc.z, 32); acc.w += __shfl_xor(acc.w, 32);
    if (lane < 16)
        *reinterpret_cast<float4*>(&sacc[wave][lane * 4]) = acc;
    __syncthreads();

    // Cross-wave reduce + mean + ReLU (dims 50..63 are zero-padding, ignored).
    if (tid < DIMV) {
        float s = sacc[0][tid] + sacc[1][tid] + sacc[2][tid] + sacc[3][tid];
        srep[tid] = fmaxf(s / (float)len, 0.f);
    }
    __syncthreads();

    // Tiny matvec: 20 outputs x 50-dot (W is 4KB, cache-resident).
    if (tid < OUTV) {
        float s = bias[tid];
        const float* wr = W + tid * DIMV;
        #pragma unroll
        for (int d = 0; d < DIMV; ++d) s += srep[d] * wr[d];
        out[b * OUTV + tid] = s;
    }
}

extern "C" void kernel_launch(void* const* d_in, const int* in_sizes, int n_in,
                              void* d_out, int out_size, void* d_ws, size_t ws_size,
                              hipStream_t stream) {
    const int*   x       = (const int*)  d_in[0];
    const int*   lengths = (const int*)  d_in[1];
    const float* emb     = (const float*)d_in[2];
    const float* W       = (const float*)d_in[3];
    const float* bias    = (const float*)d_in[4];
    float*  out = (float*)d_out;
    __half* tab = (__half*)d_ws;    // (VOCAB+1) x 64 halves = 12.8 MB

    const int B = in_sizes[1];      // 4096

    const int nthr = (VOCABSZ + 1) * 16;
    build_tab<<<(nthr + 255) / 256, 256, 0, stream>>>(emb, tab);
    fused_gather<<<B, 256, 0, stream>>>(x, lengths, tab, W, bias, out);
}

// Round 5
// 97.688 us; speedup vs baseline: 1.2694x; 1.0116x over previous
//
#include <hip/hip_runtime.h>
#include <hip/hip_fp16.h>

// Fused: embedding gather -> masked mean -> ReLU -> linear(20x50)+bias
//   VOCAB=100000, DIM=50, B=4096, L=512, OUT=20
// R4 post-mortem: FETCH is at the compulsory floor (~95MB = 8 XCDs x table,
// verified against R3's 72MB @ 10MB table). Remaining lever is fetch RATE
// (~4 TB/s vs ~6 streaming). R5: dwordx4 gathers — 8 halves/lane, 8 lanes/row,
// 8 tokens per wave-instruction (1KB/instr), halving issue work per token again.

#define LMAX    512
#define DIMV    50
#define OUTV    20
#define VOCABSZ 100000
#define RSTRIDE 64     // padded row stride in halves (128 B)

struct __align__(16) H8 { __half2 h[4]; };   // 8 halves = 16 B

// ---- Kernel 1: build padded f16 table in ws (+1 zero row at index VOCABSZ) ----
// thread t: row r = t>>3, chunk q = t&7 -> halves 8q..8q+7 (dims >=50 zero).
__global__ __launch_bounds__(256) void build_tab(
    const float* __restrict__ emb, __half* __restrict__ tab)
{
    const int t = blockIdx.x * 256 + threadIdx.x;
    const int r = t >> 3;
    const int q = t & 7;
    if (r > VOCABSZ) return;
    float v[8] = {0.f, 0.f, 0.f, 0.f, 0.f, 0.f, 0.f, 0.f};
    if (r < VOCABSZ) {
        const float* src = emb + r * DIMV + q * 8;   // 8B-aligned (200B rows)
        if (q < 6) {
            #pragma unroll
            for (int j = 0; j < 8; j += 2) {
                float2 a = *reinterpret_cast<const float2*>(src + j);
                v[j] = a.x; v[j + 1] = a.y;
            }
        } else if (q == 6) {                         // dims 48,49
            float2 a = *reinterpret_cast<const float2*>(src);
            v[0] = a.x; v[1] = a.y;
        }
    }
    H8 h;
    h.h[0] = __floats2half2_rn(v[0], v[1]);
    h.h[1] = __floats2half2_rn(v[2], v[3]);
    h.h[2] = __floats2half2_rn(v[4], v[5]);
    h.h[3] = __floats2half2_rn(v[6], v[7]);
    *reinterpret_cast<H8*>(tab + r * RSTRIDE + q * 8) = h;
}

__device__ inline void accum(float4& a0, float4& a1, const H8& h) {
    float2 f0 = __half22float2(h.h[0]);
    float2 f1 = __half22float2(h.h[1]);
    float2 f2 = __half22float2(h.h[2]);
    float2 f3 = __half22float2(h.h[3]);
    a0.x += f0.x; a0.y += f0.y; a0.z += f1.x; a0.w += f1.y;
    a1.x += f2.x; a1.y += f2.y; a1.z += f3.x; a1.w += f3.y;
}

// ---- Kernel 2: fused gather/mean/relu/linear. One block per sample. ----
// lane = 8*rg + cl: row-group rg in [0,8) (token-in-chunk), column cl in [0,8)
// (8 halves each). One load instruction = 8 tokens x 128 B = 1 KB coalesced.
__global__ __launch_bounds__(256) void fused_gather(
    const int*    __restrict__ x,
    const int*    __restrict__ lengths,
    const __half* __restrict__ tab,
    const float*  __restrict__ W,
    const float*  __restrict__ bias,
    float*        __restrict__ out)
{
    const int b    = blockIdx.x;
    const int tid  = threadIdx.x;
    const int wave = tid >> 6;
    const int lane = tid & 63;
    const int rg   = lane >> 3;     // which row of the 8-token chunk
    const int cl   = lane & 7;      // 8-half column within row

    __shared__ int   sidx[LMAX];
    __shared__ float sacc[4][64];
    __shared__ float srep[DIMV];

    const int len = lengths[b];

    // Stage all 512 indices; tokens >= len point at the zero row (branch-free hot loop).
    const int xbase = b * LMAX;
    #pragma unroll
    for (int i = 0; i < LMAX; i += 256) {
        const int ii = i + tid;
        const int v  = x[xbase + ii];
        sidx[ii] = (ii < len) ? v : VOCABSZ;
    }
    __syncthreads();

    const __half* tabc = tab + cl * 8;       // lane-constant column base (16B-aligned)
    const int nchunk = (len + 7) >> 3;       // 8-token chunks (max 64)
    float4 a0 = {0.f, 0.f, 0.f, 0.f};
    float4 a1 = {0.f, 0.f, 0.f, 0.f};

    int c = wave;
    // 8 chunks (64 tokens, 8 x 1KB loads) in flight per wave.
    for (; c + 28 < nchunk; c += 32) {
        int i0 = sidx[(c     ) * 8 + rg];
        int i1 = sidx[(c +  4) * 8 + rg];
        int i2 = sidx[(c +  8) * 8 + rg];
        int i3 = sidx[(c + 12) * 8 + rg];
        int i4 = sidx[(c + 16) * 8 + rg];
        int i5 = sidx[(c + 20) * 8 + rg];
        int i6 = sidx[(c + 24) * 8 + rg];
        int i7 = sidx[(c + 28) * 8 + rg];
        H8 h0 = *reinterpret_cast<const H8*>(tabc + (i0 << 6));
        H8 h1 = *reinterpret_cast<const H8*>(tabc + (i1 << 6));
        H8 h2 = *reinterpret_cast<const H8*>(tabc + (i2 << 6));
        H8 h3 = *reinterpret_cast<const H8*>(tabc + (i3 << 6));
        H8 h4 = *reinterpret_cast<const H8*>(tabc + (i4 << 6));
        H8 h5 = *reinterpret_cast<const H8*>(tabc + (i5 << 6));
        H8 h6 = *reinterpret_cast<const H8*>(tabc + (i6 << 6));
        H8 h7 = *reinterpret_cast<const H8*>(tabc + (i7 << 6));
        accum(a0, a1, h0); accum(a0, a1, h1); accum(a0, a1, h2); accum(a0, a1, h3);
        accum(a0, a1, h4); accum(a0, a1, h5); accum(a0, a1, h6); accum(a0, a1, h7);
    }
    for (; c < nchunk; c += 4) {
        int i0 = sidx[c * 8 + rg];
        H8 h0 = *reinterpret_cast<const H8*>(tabc + (i0 << 6));
        accum(a0, a1, h0);
    }

    // Sum the 8 row-groups (butterfly over lane bits 3,4,5). Lanes 0-7 hold result.
    #pragma unroll
    for (int m = 8; m <= 32; m <<= 1) {
        a0.x += __shfl_xor(a0.x, m); a0.y += __shfl_xor(a0.y, m);
        a0.z += __shfl_xor(a0.z, m); a0.w += __shfl_xor(a0.w, m);
        a1.x += __shfl_xor(a1.x, m); a1.y += __shfl_xor(a1.y, m);
        a1.z += __shfl_xor(a1.z, m); a1.w += __shfl_xor(a1.w, m);
    }
    if (lane < 8) {
        *reinterpret_cast<float4*>(&sacc[wave][lane * 8])     = a0;
        *reinterpret_cast<float4*>(&sacc[wave][lane * 8 + 4]) = a1;
    }
    __syncthreads();

    // Cross-wave reduce + mean + ReLU (dims 50..63 are zero-padding, ignored).
    if (tid < DIMV) {
        float s = sacc[0][tid] + sacc[1][tid] + sacc[2][tid] + sacc[3][tid];
        srep[tid] = fmaxf(s / (float)len, 0.f);
    }
    __syncthreads();

    // Tiny matvec: 20 outputs x 50-dot (W is 4KB, cache-resident).
    if (tid < OUTV) {
        float s = bias[tid];
        const float* wr = W + tid * DIMV;
        #pragma unroll
        for (int d = 0; d < DIMV; ++d) s += srep[d] * wr[d];
        out[b * OUTV + tid] = s;
    }
}

extern "C" void kernel_launch(void* const* d_in, const int* in_sizes, int n_in,
                              void* d_out, int out_size, void* d_ws, size_t ws_size,
                              hipStream_t stream) {
    const int*   x       = (const int*)  d_in[0];
    const int*   lengths = (const int*)  d_in[1];
    const float* emb     = (const float*)d_in[2];
    const float* W       = (const float*)d_in[3];
    const float* bias    = (const float*)d_in[4];
    float*  out = (float*)d_out;
    __half* tab = (__half*)d_ws;    // (VOCAB+1) x 64 halves = 12.8 MB

    const int B = in_sizes[1];      // 4096

    const int nthr = (VOCABSZ + 1) * 8;
    build_tab<<<(nthr + 255) / 256, 256, 0, stream>>>(emb, tab);
    fused_gather<<<B, 256, 0, stream>>>(x, lengths, tab, W, bias, out);
}